// Round 14
// baseline (313.079 us; speedup 1.0000x reference)
//
#include <hip/hip_runtime.h>
#include <stdint.h>

#define B_ 4
#define T_ 4096
#define D_ 1024
#define H_ 16
#define NPAD 2304            // 1024 k + 1024 v + 16 beta + 16 g + 224 zero-pad (multiple of 256)
#define ROWS (B_*T_)         // 16384

typedef __bf16 bf16x8 __attribute__((ext_vector_type(8)));
typedef float  f32x4  __attribute__((ext_vector_type(4)));
typedef unsigned short u16;
typedef u16 u16x8 __attribute__((ext_vector_type(8)));
typedef u16 u16x4 __attribute__((ext_vector_type(4)));

__device__ __forceinline__ float bf2f(u16 u){
  union { unsigned int i; float f; } x; x.i = ((unsigned int)u) << 16; return x.f;
}
__device__ __forceinline__ u16 f2bf(float f){
  union { float f; unsigned int i; } x; x.f = f;
  unsigned int r = x.i + 0x7fffu + ((x.i >> 16) & 1u);
  return (u16)(r >> 16);
}
__device__ __forceinline__ bf16x8 as_bf(u16x8 v){ union{u16x8 u; bf16x8 b;} x; x.u = v; return x.b; }

__device__ __forceinline__ void gload_lds16(const u16* g, u16* l){
  __builtin_amdgcn_global_load_lds(
      (const __attribute__((address_space(1))) unsigned int*)g,
      (__attribute__((address_space(3))) unsigned int*)l, 16, 0, 0);
}

// ---------------- fused weight-prep + RMSNorm (grid-partitioned) ----------------
__global__ __launch_bounds__(256) void prep_rms(
    const float* __restrict__ x, const float* __restrict__ w,
    const float* __restrict__ Wk, const float* __restrict__ Wv,
    const float* __restrict__ Wb, const float* __restrict__ Wg,
    const float* __restrict__ Wo,
    u16* __restrict__ xn, u16* __restrict__ Wcomb, u16* __restrict__ Wob)
{
  const int bid = blockIdx.x;
  const int tid = threadIdx.x;
  if (bid < ROWS) {
    long row = bid;
    int l = tid & 63, wv = tid >> 6;
    f32x4 v = ((const f32x4*)(x + row * D_))[tid];
    float ss = v[0]*v[0] + v[1]*v[1] + v[2]*v[2] + v[3]*v[3];
    #pragma unroll
    for (int m = 1; m < 64; m <<= 1) ss += __shfl_xor(ss, m, 64);
    __shared__ float red[4];
    if (l == 0) red[wv] = ss;
    __syncthreads();
    float tot = red[0] + red[1] + red[2] + red[3];
    float inv = rsqrtf(tot * (1.f / (float)D_) + 1e-6f);
    f32x4 wv4 = ((const f32x4*)w)[tid];
    u16x4 o;
    o[0] = f2bf(v[0] * inv * wv4[0]);
    o[1] = f2bf(v[1] * inv * wv4[1]);
    o[2] = f2bf(v[2] * inv * wv4[2]);
    o[3] = f2bf(v[3] * inv * wv4[3]);
    ((u16x4*)(xn + row * D_))[tid] = o;
  } else {
    long i = (long)(bid - ROWS) * 256 + tid;
    const long tot1 = (long)NPAD * D_;
    if (i < tot1) {
      long n = i >> 10, d = i & 1023;
      float v;
      if      (n < 1024) v = Wk[n * 1024 + d];
      else if (n < 2048) v = Wv[(n - 1024) * 1024 + d];
      else if (n < 2064) v = Wb[(n - 2048) * 1024 + d];
      else if (n < 2080) v = Wg[(n - 2064) * 1024 + d];
      else               v = 0.f;
      Wcomb[i] = f2bf(v);
    } else {
      long j = i - tot1;
      Wob[j] = f2bf(Wo[j]);
    }
  }
}

extern __shared__ f32x4 lds_dyn[];

// ---------------- 256x256 8-phase counted-vmcnt bf16 NT GEMM (v2) ----------------
// BK=64 as 4 half-tiles/tile {A-ks0,B-ks0,A-ks1,B-ks1}, 8 slots x 16KB (128KB).
// Phase p: {ds_reads; stage half p+6; [vmcnt(6) iff p even]; barrier; 16 MFMA
// (setprio); barrier}. NO explicit lgkmcnt / sched_barrier (compiler pipelines
// counted lgkmcnt into the MFMA cluster). Proven-conflict-free swizzle
// (chunk j ^= (row>>1)&3 both-sides, = R5/R6 gemm256 algebra).
// Ledger: even phase q confirms halves <= q+3; reads at p need <= p+1 (q=p-2) OK;
// evict half p-2 last-read <= p-1 < stage OK; live slots p-1..p+6 = 8 OK.
template<int RESID, int OUTF32>
__global__ __launch_bounds__(512, 2) void gemm8p2(
    const u16* __restrict__ A, const u16* __restrict__ Bm,
    u16* __restrict__ Cb, float* __restrict__ Cf, const float* __restrict__ resid,
    int M, int N, int Kd)
{
  const int tid = threadIdx.x;
  const int w = tid >> 6, l = tid & 63;
  const int lm = l & 15, lq = l >> 4;
  const int wm = w >> 2, wn = w & 3;

  unsigned gx = gridDim.x;
  unsigned bid = blockIdx.y * gx + blockIdx.x;
  unsigned nwg = gx * gridDim.y;
  unsigned cpx = nwg >> 3;
  unsigned swz = (bid & 7) * cpx + (bid >> 3);
  const long bm0 = (long)(swz / gx) * 256;
  const long bn0 = (long)(swz % gx) * 256;

  char* lds = (char*)lds_dyn;
  const int NTS = Kd >> 6;      // 16
  const int NH  = NTS * 4;      // 64 halves

  // stage half H: [256 rows][32 k] bf16 = 16KB; 2 x 16B/thread; linear LDS dest,
  // global k-chunk = (c&3) ^ ((row>>1)&3) = (c&3) ^ ((c>>3)&3).
  auto STAGE_H = [&](int H){
    if (H >= NH) return;
    int kind = H & 3, tau = H >> 2;
    long k0 = (long)tau*64 + (kind >> 1)*32;
    u16* base = (u16*)(lds + (H & 7)*16384);
    #pragma unroll
    for (int q = 0; q < 2; ++q) {
      int c = q*512 + tid;
      int row = c >> 2;
      int jp = (c & 3) ^ ((c >> 3) & 3);
      const u16* src = ((kind & 1) == 0)
          ? (A  + (bm0 + row)*(long)Kd + k0 + jp*8)
          : (Bm + (bn0 + row)*(long)Kd + k0 + jp*8);
      gload_lds16(src, base + c*8);
    }
  };

  const unsigned soff = (unsigned)(lq ^ ((lm >> 1) & 3)) << 4;

  f32x4 acc[8][4];
  #pragma unroll
  for (int i = 0; i < 8; ++i)
    #pragma unroll
    for (int j = 0; j < 4; ++j) acc[i][j] = f32x4{0.f,0.f,0.f,0.f};

  bf16x8 afr[4], bfr[4];

  auto RD_A = [&](int tau, int ks, int mh){
    const char* base = lds + (((tau*4 + ks*2) & 7) * 16384);
    #pragma unroll
    for (int mi = 0; mi < 4; ++mi) {
      int rr = wm*128 + mh*64 + mi*16 + lm;
      afr[mi] = *(const bf16x8*)(base + rr*64 + soff);
    }
  };
  auto RD_B = [&](int tau, int ks){
    const char* base = lds + (((tau*4 + ks*2 + 1) & 7) * 16384);
    #pragma unroll
    for (int ni = 0; ni < 4; ++ni) {
      int rr = wn*64 + ni*16 + lm;
      bfr[ni] = *(const bf16x8*)(base + rr*64 + soff);
    }
  };
  auto MMQ = [&](int mh){
    __builtin_amdgcn_s_setprio(1);
    #pragma unroll
    for (int mi = 0; mi < 4; ++mi)
      #pragma unroll
      for (int ni = 0; ni < 4; ++ni)
        acc[mh*4 + mi][ni] = __builtin_amdgcn_mfma_f32_16x16x32_bf16(
            afr[mi], bfr[ni], acc[mh*4 + mi][ni], 0, 0, 0);
    __builtin_amdgcn_s_setprio(0);
  };

  // prologue: stage halves 0..5 (12 loads); vmcnt(2) -> halves 0..4 complete.
  STAGE_H(0); STAGE_H(1); STAGE_H(2); STAGE_H(3); STAGE_H(4); STAGE_H(5);
  asm volatile("s_waitcnt vmcnt(2)" ::: "memory");
  __builtin_amdgcn_s_barrier();
  asm volatile("" ::: "memory");

  for (int tau = 0; tau < NTS; ++tau) {
    const int p0 = tau*4;
    // ph0 (even): reads halves p0, p0+1
    RD_A(tau, 0, 0);
    RD_B(tau, 0);
    STAGE_H(p0 + 6);
    asm volatile("s_waitcnt vmcnt(6)" ::: "memory");
    __builtin_amdgcn_s_barrier();
    asm volatile("" ::: "memory");
    MMQ(0);
    __builtin_amdgcn_s_barrier();
    asm volatile("" ::: "memory");
    // ph1: re-reads half p0 (A-ks0, mh1); B reused in regs
    RD_A(tau, 0, 1);
    STAGE_H(p0 + 7);
    __builtin_amdgcn_s_barrier();
    asm volatile("" ::: "memory");
    MMQ(1);
    __builtin_amdgcn_s_barrier();
    asm volatile("" ::: "memory");
    // ph2 (even): reads halves p0+2, p0+3
    RD_A(tau, 1, 0);
    RD_B(tau, 1);
    STAGE_H(p0 + 8);
    asm volatile("s_waitcnt vmcnt(6)" ::: "memory");
    __builtin_amdgcn_s_barrier();
    asm volatile("" ::: "memory");
    MMQ(0);
    __builtin_amdgcn_s_barrier();
    asm volatile("" ::: "memory");
    // ph3: re-reads half p0+2 (A-ks1, mh1)
    RD_A(tau, 1, 1);
    STAGE_H(p0 + 9);
    __builtin_amdgcn_s_barrier();
    asm volatile("" ::: "memory");
    MMQ(1);
    __builtin_amdgcn_s_barrier();
    asm volatile("" ::: "memory");
  }

  #pragma unroll
  for (int mf = 0; mf < 8; ++mf) {
    #pragma unroll
    for (int r = 0; r < 4; ++r) {
      long m = bm0 + wm*128 + mf*16 + lq*4 + r;
      #pragma unroll
      for (int nf = 0; nf < 4; ++nf) {
        long n = bn0 + wn*64 + nf*16 + lm;
        float val = acc[mf][nf][r];
        if (RESID) val += resid[m * N + n];
        if (OUTF32) Cf[m * N + n] = val;
        else        Cb[m * N + n] = f2bf(val);
      }
    }
  }
}

// ---------------- 256x256 deep-pipelined bf16 NT GEMM (R6-proven; gemm2 + fallback) ----------------
template<int RESID, int OUTF32>
__global__ __launch_bounds__(512, 2) void gemm256(
    const u16* __restrict__ A, const u16* __restrict__ Bm,
    u16* __restrict__ Cb, float* __restrict__ Cf, const float* __restrict__ resid,
    int M, int N, int Kd)
{
  const int tid = threadIdx.x;
  const int w = tid >> 6, l = tid & 63;
  const int lm = l & 15, lq = l >> 4;
  const int wm = w >> 2, wn = w & 3;

  unsigned gx = gridDim.x;
  unsigned bid = blockIdx.y * gx + blockIdx.x;
  unsigned nwg = gx * gridDim.y;
  unsigned cpx = nwg >> 3;
  unsigned swz = (bid & 7) * cpx + (bid >> 3);
  const long bm0 = (long)(swz / gx) * 256;
  const long bn0 = (long)(swz % gx) * 256;

  char* lds = (char*)lds_dyn;

  int rowS[2];
  #pragma unroll
  for (int r = 0; r < 2; ++r) rowS[r] = r*128 + w*16 + (l >> 2);
  const int colS = ((l & 3) ^ ((l >> 3) & 3)) * 8;

  auto STAGE_A = [&](int t, int q){
    char* base = lds + q*32768;
    long k0 = (long)t * 32;
    #pragma unroll
    for (int r = 0; r < 2; ++r)
      gload_lds16(A + (bm0 + rowS[r])*(long)Kd + k0 + colS,
                  (u16*)(base + (r*512 + w*64)*16));
  };
  auto STAGE_B = [&](int t, int q){
    char* base = lds + q*32768 + 16384;
    long k0 = (long)t * 32;
    #pragma unroll
    for (int r = 0; r < 2; ++r)
      gload_lds16(Bm + (bn0 + rowS[r])*(long)Kd + k0 + colS,
                  (u16*)(base + (r*512 + w*64)*16));
  };

  const unsigned soff = (unsigned)(lq ^ ((lm >> 1) & 3)) << 4;

  f32x4 acc[8][4];
  #pragma unroll
  for (int i = 0; i < 8; ++i)
    #pragma unroll
    for (int j = 0; j < 4; ++j) acc[i][j] = f32x4{0.f,0.f,0.f,0.f};

  const int NT = Kd >> 5;     // 32
  STAGE_A(0, 0); STAGE_B(0, 0);
  STAGE_A(1, 1); STAGE_B(1, 1);

  for (int t = 0; t < NT; ++t) {
    int q  = t % 3;
    int qn = (t + 2) % 3;
    int tn = (t + 2 < NT) ? (t + 2) : (NT - 1);

    asm volatile("s_waitcnt vmcnt(4)" ::: "memory");
    __builtin_amdgcn_s_barrier();
    asm volatile("" ::: "memory");

    const char* Ab = lds + q*32768;
    const char* Bb = Ab + 16384;

    bf16x8 bfr[4], afr[8];
    #pragma unroll
    for (int nf = 0; nf < 4; ++nf) {
      int rr = wn*64 + nf*16 + lm;
      bfr[nf] = *(const bf16x8*)(Bb + rr*64 + soff);
    }
    #pragma unroll
    for (int mf = 0; mf < 8; ++mf) {
      int rr = wm*128 + mf*16 + lm;
      afr[mf] = *(const bf16x8*)(Ab + rr*64 + soff);
    }
    STAGE_A(tn, qn);
    STAGE_B(tn, qn);

    __builtin_amdgcn_s_setprio(1);
    #pragma unroll
    for (int mf = 0; mf < 8; ++mf)
      #pragma unroll
      for (int nf = 0; nf < 4; ++nf)
        acc[mf][nf] = __builtin_amdgcn_mfma_f32_16x16x32_bf16(afr[mf], bfr[nf], acc[mf][nf], 0, 0, 0);
    __builtin_amdgcn_s_setprio(0);
  }

  #pragma unroll
  for (int mf = 0; mf < 8; ++mf) {
    #pragma unroll
    for (int r = 0; r < 4; ++r) {
      long m = bm0 + wm*128 + mf*16 + lq*4 + r;
      #pragma unroll
      for (int nf = 0; nf < 4; ++nf) {
        long n = bn0 + wn*64 + nf*16 + lm;
        float val = acc[mf][nf][r];
        if (RESID) val += resid[m * N + n];
        if (OUTF32) Cf[m * N + n] = val;
        else        Cb[m * N + n] = f2bf(val);
      }
    }
  }
}

// 64x64x64 NT matmul from LDS bf16 tiles (stride 72)
__device__ __forceinline__ void mm64(const u16* Ab, const u16* Bb,
                                     int lm, int lq, int wr, int wc, f32x4 acc[2][2])
{
  #pragma unroll
  for (int ks = 0; ks < 2; ++ks) {
    bf16x8 af[2], bfr[2];
    #pragma unroll
    for (int mi = 0; mi < 2; ++mi)
      af[mi] = *(const bf16x8*)(Ab + (wr*32 + mi*16 + lm)*72 + ks*32 + lq*8);
    #pragma unroll
    for (int ni = 0; ni < 2; ++ni)
      bfr[ni] = *(const bf16x8*)(Bb + (wc*32 + ni*16 + lm)*72 + ks*32 + lq*8);
    #pragma unroll
    for (int mi = 0; mi < 2; ++mi)
      #pragma unroll
      for (int ni = 0; ni < 2; ++ni)
        acc[mi][ni] = __builtin_amdgcn_mfma_f32_16x16x32_bf16(af[mi], bfr[ni], acc[mi][ni], 0, 0, 0);
  }
}

// ---------------- phase 1: per-chunk WY factors (sigmoid folded in) ----------------
__global__ __launch_bounds__(256) void chunk1(
    u16* __restrict__ kv, const float* __restrict__ bb, const float* __restrict__ bg,
    u16* __restrict__ p1buf, u16* __restrict__ r1buf)
{
  __shared__ __align__(16) u16 Kb[64*72];
  __shared__ __align__(16) u16 Utb[128*72];
  __shared__ __align__(16) u16 LpI[64*72];
  __shared__ __align__(16) u16 Abf[64*72];
  __shared__ __align__(16) u16 Adb[4*16*24];
  __shared__ float nrm2LS[64];
  __shared__ float aLS[64], ainvLS[64], bLS[64], bapLS[64];
  __shared__ float aCsh;

  const int tid = threadIdx.x;
  const int w = tid >> 6, l = tid & 63;
  const int lm = l & 15, lq = l >> 4;
  const int wr = w >> 1, wc = w & 1;
  const int bh = blockIdx.x & 63, ch = blockIdx.x >> 6;
  const int b = bh >> 4, h = bh & 15;

  const u16* kbase = kv + ((long)b*T_ + ch*64)*NPAD + h*64;
  const u16* vbase = kbase + 1024;

  #pragma unroll
  for (int it = 0; it < 2; ++it) {
    int c = tid + it*256;
    int r = c >> 3, seg = (c & 7)*8;
    *(u16x8*)(Kb  + r*72 + seg) = *(const u16x8*)(kbase + (long)r*NPAD + seg);
    *(u16x8*)(Utb + r*72 + seg) = *(const u16x8*)(vbase + (long)r*NPAD + seg);
  }
  #pragma unroll
  for (int z = 0; z < 8; ++z) {
    int idx = tid + z*256;
    int rr = idx >> 5, wd = idx & 31;
    ((unsigned int*)(Utb + (64 + rr)*72))[wd] = 0u;
  }
  if (tid < 64) {
    long rowg = ((long)b*T_ + ch*64 + tid) * NPAD;
    float blog = bf2f(kv[rowg + 2048 + h]) + bb[h];
    float glog = bf2f(kv[rowg + 2064 + h]) + bg[h];
    float bv = 1.f / (1.f + expf(-blog));
    float gv = 1.f / (1.f + expf(-glog));
    float av = gv;
    #pragma unroll
    for (int off = 1; off < 64; off <<= 1) {
      float o = __shfl_up(av, off, 64);
      if (tid >= off) av *= o;
    }
    float ap = __shfl_up(av, 1, 64);
    if (tid == 0) ap = 1.f;
    float aC = __shfl(av, 63, 64);
    aLS[tid] = av; ainvLS[tid] = 1.f/av; bLS[tid] = bv; bapLS[tid] = bv*ap;
    if (tid == 0) aCsh = aC;
  }
  __syncthreads();

  f32x4 gf[2][2];
  #pragma unroll
  for (int mi = 0; mi < 2; ++mi)
    #pragma unroll
    for (int ni = 0; ni < 2; ++ni) gf[mi][ni] = f32x4{0.f,0.f,0.f,0.f};
  mm64(Kb, Kb, lm, lq, wr, wc, gf);

  #pragma unroll
  for (int mi = 0; mi < 2; ++mi)
    #pragma unroll
    for (int ni = 0; ni < 2; ++ni)
      #pragma unroll
      for (int r = 0; r < 4; ++r) {
        int row = wr*32 + mi*16 + lq*4 + r, col = wc*32 + ni*16 + lm;
        if (row == col) nrm2LS[row] = gf[mi][ni][r];
      }
  __syncthreads();
  if (tid < 64) {
    float nv = 1.f / fmaxf(sqrtf(nrm2LS[tid]), 1e-12f);
    aLS[tid] *= nv; ainvLS[tid] *= nv; bapLS[tid] *= nv;
  }
  __syncthreads();

  float wv_[4][2][4];
  #pragma unroll
  for (int bi = 0; bi < 4; ++bi)
    #pragma unroll
    for (int ni = 0; ni < 2; ++ni) {
      int col = w*32 + ni*16 + lm;
      #pragma unroll
      for (int r = 0; r < 4; ++r) {
        int row = bi*16 + lq*4 + r;
        float sv = (col < 64) ? bf2f(Utb[row*72 + col]) : bf2f(Kb[row*72 + (col - 64)]);
        float coef = (col < 64) ? bLS[row] : bapLS[row];
        wv_[bi][ni][r] = coef * sv;
      }
    }

  #pragma unroll
  for (int mi = 0; mi < 2; ++mi)
    #pragma unroll
    for (int ni = 0; ni < 2; ++ni)
      #pragma unroll
      for (int r = 0; r < 4; ++r) {
        int row = wr*32 + mi*16 + lq*4 + r, col = wc*32 + ni*16 + lm;
        float gvl = gf[mi][ni][r];
        int rb = row >> 4, cb = col >> 4;
        Abf[row*72 + col] = f2bf((rb > cb) ? bapLS[row]*ainvLS[col]*gvl : 0.f);
        if (rb == cb)
          Adb[rb*384 + (row & 15)*24 + (col & 15)] =
              f2bf(((col & 15) < (row & 15)) ? bapLS[row]*ainvLS[col]*gvl : 0.f);
        LpI[row*72 + col] = f2bf((col < row) ? aLS[row]*ainvLS[col]*gvl
                                             : ((col == row) ? 1.f : 0.f));
      }
  __syncthreads();

  #pragma unroll
  for (int bi = 0; bi < 4; ++bi) {
    if (bi > 0) {
      f32x4 corr[2] = { f32x4{0.f,0.f,0.f,0.f}, f32x4{0.f,0.f,0.f,0.f} };
      const int nks = (bi*16 + 31) >> 5;
      #pragma unroll
      for (int ks = 0; ks < 2; ++ks) {
        if (ks < nks) {
          bf16x8 afr = *(const bf16x8*)(Abf + (bi*16 + lm)*72 + ks*32 + lq*8);
          #pragma unroll
          for (int ni = 0; ni < 2; ++ni) {
            bf16x8 bfrv = *(const bf16x8*)(Utb + (w*32 + ni*16 + lm)*72 + ks*32 + lq*8);
            corr[ni] = __builtin_amdgcn_mfma_f32_16x16x32_bf16(afr, bfrv, corr[ni], 0, 0, 0);
          }
        }
      }
      #pragma unroll
      for (int ni = 0; ni < 2; ++ni)
        #pragma unroll
        for (int r = 0; r < 4; ++r) wv_[bi][ni][r] -= corr[ni][r];
    }
    u16x8 ad0[4], ad1[4];
    #pragma unroll
    for (int r = 0; r < 4; ++r) {
      ad0[r] = *(const u16x8*)(Adb + bi*384 + (lq*4 + r)*24);
      ad1[r] = *(const u16x8*)(Adb + bi*384 + (lq*4 + r)*24 + 8);
    }
    #pragma unroll
    for (int i = 0; i < 16; ++i) {
      int src = ((i >> 2) << 4) | lm;
      float u0 = __shfl(wv_[bi][0][i & 3], src, 64);
      float u1 = __shfl(wv_[bi][1][i & 3], src, 64);
      #pragma unroll
      for (int r = 0; r < 4; ++r) {
        float ad = bf2f((i < 8) ? ad0[r][i] : ad1[r][i - 8]);
        wv_[bi][0][r] = fmaf(-ad, u0, wv_[bi][0][r]);
        wv_[bi][1][r] = fmaf(-ad, u1, wv_[bi][1][r]);
      }
    }
    #pragma unroll
    for (int ni = 0; ni < 2; ++ni) {
      int col = w*32 + ni*16 + lm;
      #pragma unroll
      for (int r = 0; r < 4; ++r)
        Utb[col*72 + bi*16 + lq*4 + r] = f2bf(wv_[bi][ni][r]);
    }
  }
  __syncthreads();

  const long pr_base = (((long)bh*64 + ch)*64);
  u16* qdst = kv + ((long)b*T_ + ch*64)*NPAD + h*64;
  u16* mdst = qdst + 1024;
  f32x4 acc[2][2];

  // P1[i][v]
  #pragma unroll
  for (int mi = 0; mi < 2; ++mi)
    #pragma unroll
    for (int ni = 0; ni < 2; ++ni) acc[mi][ni] = f32x4{0.f,0.f,0.f,0.f};
  mm64(LpI, Utb, lm, lq, wr, wc, acc);
  #pragma unroll
  for (int mi = 0; mi < 2; ++mi)
    #pragma unroll
    for (int ni = 0; ni < 2; ++ni)
      #pragma unroll
      for (int r = 0; r < 4; ++r) {
        int row = wr*32 + mi*16 + lq*4 + r, col = wc*32 + ni*16 + lm;
        p1buf[(pr_base + row)*64 + col] = f2bf(acc[mi][ni][r]);
      }

  // Q
  #pragma unroll
  for (int mi = 0; mi < 2; ++mi)
    #pragma unroll
    for (int ni = 0; ni < 2; ++ni) acc[mi][ni] = f32x4{0.f,0.f,0.f,0.f};
  mm64(LpI, Utb + 64*72, lm, lq, wr, wc, acc);
  #pragma unroll
  for (int mi = 0; mi < 2; ++mi)
    #pragma unroll
    for (int ni = 0; ni < 2; ++ni)
      #pragma unroll
      for (int r = 0; r < 4; ++r) {
        int row = wr*32 + mi*16 + lq*4 + r, col = wc*32 + ni*16 + lm;
        float val = aLS[row]*bf2f(Kb[row*72 + col]) - acc[mi][ni][r];
        qdst[(long)row*NPAD + col] = f2bf(val);
      }

  // Ktb into Abf
  {
    int s = tid & 63, kk0 = (tid >> 6) * 16;
    float coef = aCsh * ainvLS[s];
    #pragma unroll
    for (int j = 0; j < 16; ++j)
      Abf[(kk0 + j)*72 + s] = f2bf(coef * bf2f(Kb[s*72 + kk0 + j]));
  }
  __syncthreads();

  // R1[k][v]
  #pragma unroll
  for (int mi = 0; mi < 2; ++mi)
    #pragma unroll
    for (int ni = 0; ni < 2; ++ni) acc[mi][ni] = f32x4{0.f,0.f,0.f,0.f};
  mm64(Abf, Utb, lm, lq, wr, wc, acc);
  #pragma unroll
  for (int mi = 0; mi < 2; ++mi)
    #pragma unroll
    for (int ni = 0; ni < 2; ++ni)
      #pragma unroll
      for (int r = 0; r < 4; ++r) {
        int row = wr*32 + mi*16 + lq*4 + r, col = wc*32 + ni*16 + lm;
        r1buf[(pr_base + row)*64 + col] = f2bf(acc[mi][ni][r]);
      }

  // M
  #pragma unroll
  for (int mi = 0; mi < 2; ++mi)
    #pragma unroll
    for (int ni = 0; ni < 2; ++ni) acc[mi][ni] = f32x4{0.f,0.f,0.f,0.f};
  mm64(Abf, Utb + 64*72, lm, lq, wr, wc, acc);
  #pragma unroll
  for (int mi = 0; mi < 2; ++mi)
    #pragma unroll
    for (int ni = 0; ni < 2; ++ni)
      #pragma unroll
      for (int r = 0; r < 4; ++r) {
        int row = wr*32 + mi*16 + lq*4 + r, col = wc*32 + ni*16 + lm;
        float val = ((row == col) ? aCsh : 0.f) - acc[mi][ni][r];
        mdst[(long)row*NPAD + col] = f2bf(val);
      }
}

// ---------------- phase 2: sequential chunk recurrence (single-barrier dbuf) ----------------
struct PF { u16x8 qf0, qf1, mf0, mf1; u16x4 p1, r1; };

__global__ __launch_bounds__(256) void chunk2(
    const u16* __restrict__ kv, const u16* __restrict__ p1buf, const u16* __restrict__ r1buf,
    u16* __restrict__ outb)
{
  __shared__ __align__(16) u16 Zb[2][16*72];
  __shared__ __align__(16) u16 ot[2][64*24];
  const int tid = threadIdx.x;
  const int wcv = tid >> 6, l = tid & 63;
  const int lm = l & 15, lq = l >> 4;
  const int bh = blockIdx.x & 63, vg = blockIdx.x >> 6;
  const int b = bh >> 4, h = bh & 15;

  for (int idx = tid; idx < 16*72/2; idx += 256) ((unsigned int*)Zb[0])[idx] = 0u;

  const u16* pbase = p1buf + (long)bh*64*4096;
  const u16* rbase = r1buf + (long)bh*64*4096;
  const int i2 = tid >> 2, q4 = tid & 3;

  auto LOADPF = [&](int ch, PF& p){
    long rq = ((long)b*T_ + ch*64 + wcv*16 + lm)*NPAD + h*64 + lq*8;
    p.qf0 = *(const u16x8*)(kv + rq);
    p.qf1 = *(const u16x8*)(kv + rq + 32);
    p.mf0 = *(const u16x8*)(kv + rq + 1024);
    p.mf1 = *(const u16x8*)(kv + rq + 1024 + 32);
    long pv = (long)ch*4096 + (wcv*16 + lm)*64 + vg*16 + lq*4;
    p.p1 = *(const u16x4*)(pbase + pv);
    p.r1 = *(const u16x4*)(rbase + pv);
  };

  PF A, Bp;
  LOADPF(0, A);
  __syncthreads();

  auto STEP = [&](int ch, PF& use, PF& pre){
    int p = ch & 1;
    bf16x8 za0 = *(const bf16x8*)(Zb[p] + lm*72 + lq*8);
    bf16x8 za1 = *(const bf16x8*)(Zb[p] + lm*72 + 32 + lq*8);
    if (ch < 63) LOADPF(ch + 1, pre);
    f32x4 accO = { bf2f(use.p1[0]), bf2f(use.p1[1]), bf2f(use.p1[2]), bf2f(use.p1[3]) };
    accO = __builtin_amdgcn_mfma_f32_16x16x32_bf16(za0, as_bf(use.qf0), accO, 0, 0, 0);
    accO = __builtin_amdgcn_mfma_f32_16x16x32_bf16(za1, as_bf(use.qf1), accO, 0, 0, 0);
    f32x4 accS = { bf2f(use.r1[0]), bf2f(use.r1[1]), bf2f(use.r1[2]), bf2f(use.r1[3]) };
    accS = __builtin_amdgcn_mfma_f32_16x16x32_bf16(za0, as_bf(use.mf0), accS, 0, 0, 0);
    accS = __builtin_amdgcn_mfma_f32_16x16x32_bf16(za1, as_bf(use.mf1), accS, 0, 0, 0);
    if (ch > 0) {
      u16x4 ov = *(const u16x4*)(ot[p^1] + i2*24 + q4*4);
      *(u16x4*)(outb + ((long)b*T_ + (ch-1)*64 + i2)*D_ + h*64 + vg*16 + q4*4) = ov;
    }
    #pragma unroll
    for (int r = 0; r < 4; ++r) ot[p][(wcv*16 + lm)*24 + lq*4 + r] = f2bf(accO[r]);
    #pragma unroll
    for (int r = 0; r < 4; ++r) Zb[p^1][(lq*4 + r)*72 + wcv*16 + lm] = f2bf(accS[r]);
    __syncthreads();
  };

  for (int c2 = 0; c2 < 32; ++c2) {
    STEP(2*c2,     A, Bp);
    STEP(2*c2 + 1, Bp, A);
  }
  {
    u16x4 ov = *(const u16x4*)(ot[1] + i2*24 + q4*4);
    *(u16x4*)(outb + ((long)b*T_ + 63*64 + i2)*D_ + h*64 + vg*16 + q4*4) = ov;
  }
}

extern "C" void kernel_launch(void* const* d_in, const int* in_sizes, int n_in,
                              void* d_out, int out_size, void* d_ws, size_t ws_size,
                              hipStream_t stream) {
  const float* x     = (const float*)d_in[0];
  const float* normw = (const float*)d_in[1];
  const float* Wk    = (const float*)d_in[2];
  const float* Wv    = (const float*)d_in[3];
  const float* Wo    = (const float*)d_in[4];
  const float* Wb    = (const float*)d_in[5];
  const float* bb    = (const float*)d_in[6];
  const float* Wg    = (const float*)d_in[7];
  const float* bg    = (const float*)d_in[8];
  float* y = (float*)d_out;

  char* ws = (char*)d_ws;
  u16* xn    = (u16*)ws;   ws += (long)ROWS * D_ * 2;      // 33.5 MB (reused as P1)
  u16* Wcomb = (u16*)ws;   ws += (long)NPAD * D_ * 2;      // 4.7 MB
  u16* Wob   = (u16*)ws;   ws += (long)D_ * D_ * 2;        // 2 MB
  u16* kvb   = (u16*)ws;   ws += (long)ROWS * NPAD * 2;    // 75.5 MB (k,v -> Q,M in place)
  u16* outb  = (u16*)ws;   ws += (long)ROWS * D_ * 2;      // 33.5 MB
  u16* r1b   = (u16*)ws;   ws += (long)64 * 64 * 4096 * 2; // 33.5 MB  R1

  const int LDSB1 = 8 * 16384;   // 128 KB for gemm8p2 (gemm1)
  const int LDSB2 = 3 * 32768;   // 96 KB for gemm256 (gemm2)
  bool big1 = true, big2 = true;
  if (hipFuncSetAttribute(reinterpret_cast<const void*>(gemm8p2<0,0>),
        hipFuncAttributeMaxDynamicSharedMemorySize, LDSB1) != hipSuccess) big1 = false;
  if (hipFuncSetAttribute(reinterpret_cast<const void*>(gemm256<0,0>),
        hipFuncAttributeMaxDynamicSharedMemorySize, LDSB2) != hipSuccess) big2 = false;
  if (hipFuncSetAttribute(reinterpret_cast<const void*>(gemm256<1,1>),
        hipFuncAttributeMaxDynamicSharedMemorySize, LDSB2) != hipSuccess) big2 = false;

  const long prep_total = (long)NPAD * D_ + (long)D_ * D_;   // 3,407,872
  const unsigned prep_blocks = (unsigned)(prep_total / 256); // 13312
  prep_rms<<<dim3(ROWS + prep_blocks), dim3(256), 0, stream>>>(
      x, normw, Wk, Wv, Wb, Wg, Wo, xn, Wcomb, Wob);
  if (big1)
    gemm8p2<0, 0><<<dim3(NPAD / 256, ROWS / 256), dim3(512), LDSB1, stream>>>(
        xn, Wcomb, kvb, (float*)nullptr, (const float*)nullptr, ROWS, NPAD, D_);
  else if (big2)
    gemm256<0, 0><<<dim3(NPAD / 256, ROWS / 256), dim3(512), LDSB2, stream>>>(
        xn, Wcomb, kvb, (float*)nullptr, (const float*)nullptr, ROWS, NPAD, D_);
  chunk1<<<dim3(4096), dim3(256), 0, stream>>>(kvb, bb, bg, xn, r1b);
  chunk2<<<dim3(256), dim3(256), 0, stream>>>(kvb, xn, r1b, outb);
  gemm256<1, 1><<<dim3(D_ / 256, ROWS / 256), dim3(512), LDSB2, stream>>>(
      outb, Wob, (u16*)nullptr, y, x, ROWS, D_, D_);
}

// Round 15
// 309.194 us; speedup vs baseline: 1.0126x; 1.0126x over previous
//
#include <hip/hip_runtime.h>
#include <stdint.h>

#define B_ 4
#define T_ 4096
#define D_ 1024
#define H_ 16
#define NPAD 2304            // 1024 k + 1024 v + 16 beta + 16 g + 224 zero-pad (multiple of 256)
#define ROWS (B_*T_)         // 16384

typedef __bf16 bf16x8 __attribute__((ext_vector_type(8)));
typedef float  f32x4  __attribute__((ext_vector_type(4)));
typedef unsigned short u16;
typedef u16 u16x8 __attribute__((ext_vector_type(8)));
typedef u16 u16x4 __attribute__((ext_vector_type(4)));

__device__ __forceinline__ float bf2f(u16 u){
  union { unsigned int i; float f; } x; x.i = ((unsigned int)u) << 16; return x.f;
}
__device__ __forceinline__ u16 f2bf(float f){
  union { float f; unsigned int i; } x; x.f = f;
  unsigned int r = x.i + 0x7fffu + ((x.i >> 16) & 1u);
  return (u16)(r >> 16);
}
__device__ __forceinline__ bf16x8 as_bf(u16x8 v){ union{u16x8 u; bf16x8 b;} x; x.u = v; return x.b; }

__device__ __forceinline__ void gload_lds16(const u16* g, u16* l){
  __builtin_amdgcn_global_load_lds(
      (const __attribute__((address_space(1))) unsigned int*)g,
      (__attribute__((address_space(3))) unsigned int*)l, 16, 0, 0);
}

// ---------------- fused weight-prep + RMSNorm (grid-partitioned) ----------------
__global__ __launch_bounds__(256) void prep_rms(
    const float* __restrict__ x, const float* __restrict__ w,
    const float* __restrict__ Wk, const float* __restrict__ Wv,
    const float* __restrict__ Wb, const float* __restrict__ Wg,
    const float* __restrict__ Wo,
    u16* __restrict__ xn, u16* __restrict__ Wcomb, u16* __restrict__ Wob)
{
  const int bid = blockIdx.x;
  const int tid = threadIdx.x;
  if (bid < ROWS) {
    long row = bid;
    int l = tid & 63, wv = tid >> 6;
    f32x4 v = ((const f32x4*)(x + row * D_))[tid];
    float ss = v[0]*v[0] + v[1]*v[1] + v[2]*v[2] + v[3]*v[3];
    #pragma unroll
    for (int m = 1; m < 64; m <<= 1) ss += __shfl_xor(ss, m, 64);
    __shared__ float red[4];
    if (l == 0) red[wv] = ss;
    __syncthreads();
    float tot = red[0] + red[1] + red[2] + red[3];
    float inv = rsqrtf(tot * (1.f / (float)D_) + 1e-6f);
    f32x4 wv4 = ((const f32x4*)w)[tid];
    u16x4 o;
    o[0] = f2bf(v[0] * inv * wv4[0]);
    o[1] = f2bf(v[1] * inv * wv4[1]);
    o[2] = f2bf(v[2] * inv * wv4[2]);
    o[3] = f2bf(v[3] * inv * wv4[3]);
    ((u16x4*)(xn + row * D_))[tid] = o;
  } else {
    long i = (long)(bid - ROWS) * 256 + tid;
    const long tot1 = (long)NPAD * D_;
    if (i < tot1) {
      long n = i >> 10, d = i & 1023;
      float v;
      if      (n < 1024) v = Wk[n * 1024 + d];
      else if (n < 2048) v = Wv[(n - 1024) * 1024 + d];
      else if (n < 2064) v = Wb[(n - 2048) * 1024 + d];
      else if (n < 2080) v = Wg[(n - 2064) * 1024 + d];
      else               v = 0.f;
      Wcomb[i] = f2bf(v);
    } else {
      long j = i - tot1;
      Wob[j] = f2bf(Wo[j]);
    }
  }
}

extern __shared__ f32x4 lds_dyn[];

// ---------------- 256x256 deep-pipelined bf16 NT GEMM (R6-proven; both GEMMs) ----------------
// BK=32, 8 waves (2x4), 3 LDS buffers (96KB dynamic), prefetch distance 2,
// ONE barrier per tile, vmcnt(4) counted (never drained), uniform-bank swizzle
// f(row)=(row>>1)&3, batched 12 ds_read -> 32 MFMA (setprio).
template<int RESID, int OUTF32>
__global__ __launch_bounds__(512, 2) void gemm256(
    const u16* __restrict__ A, const u16* __restrict__ Bm,
    u16* __restrict__ Cb, float* __restrict__ Cf, const float* __restrict__ resid,
    int M, int N, int Kd)
{
  const int tid = threadIdx.x;
  const int w = tid >> 6, l = tid & 63;
  const int lm = l & 15, lq = l >> 4;
  const int wm = w >> 2, wn = w & 3;

  unsigned gx = gridDim.x;
  unsigned bid = blockIdx.y * gx + blockIdx.x;
  unsigned nwg = gx * gridDim.y;
  unsigned cpx = nwg >> 3;
  unsigned swz = (bid & 7) * cpx + (bid >> 3);
  const long bm0 = (long)(swz / gx) * 256;
  const long bn0 = (long)(swz % gx) * 256;

  char* lds = (char*)lds_dyn;

  int rowS[2];
  #pragma unroll
  for (int r = 0; r < 2; ++r) rowS[r] = r*128 + w*16 + (l >> 2);
  const int colS = ((l & 3) ^ ((l >> 3) & 3)) * 8;

  auto STAGE_A = [&](int t, int q){
    char* base = lds + q*32768;
    long k0 = (long)t * 32;
    #pragma unroll
    for (int r = 0; r < 2; ++r)
      gload_lds16(A + (bm0 + rowS[r])*(long)Kd + k0 + colS,
                  (u16*)(base + (r*512 + w*64)*16));
  };
  auto STAGE_B = [&](int t, int q){
    char* base = lds + q*32768 + 16384;
    long k0 = (long)t * 32;
    #pragma unroll
    for (int r = 0; r < 2; ++r)
      gload_lds16(Bm + (bn0 + rowS[r])*(long)Kd + k0 + colS,
                  (u16*)(base + (r*512 + w*64)*16));
  };

  const unsigned soff = (unsigned)(lq ^ ((lm >> 1) & 3)) << 4;

  f32x4 acc[8][4];
  #pragma unroll
  for (int i = 0; i < 8; ++i)
    #pragma unroll
    for (int j = 0; j < 4; ++j) acc[i][j] = f32x4{0.f,0.f,0.f,0.f};

  const int NT = Kd >> 5;     // 32
  STAGE_A(0, 0); STAGE_B(0, 0);
  STAGE_A(1, 1); STAGE_B(1, 1);

  for (int t = 0; t < NT; ++t) {
    int q  = t % 3;
    int qn = (t + 2) % 3;
    int tn = (t + 2 < NT) ? (t + 2) : (NT - 1);

    asm volatile("s_waitcnt vmcnt(4)" ::: "memory");
    __builtin_amdgcn_s_barrier();
    asm volatile("" ::: "memory");

    const char* Ab = lds + q*32768;
    const char* Bb = Ab + 16384;

    bf16x8 bfr[4], afr[8];
    #pragma unroll
    for (int nf = 0; nf < 4; ++nf) {
      int rr = wn*64 + nf*16 + lm;
      bfr[nf] = *(const bf16x8*)(Bb + rr*64 + soff);
    }
    #pragma unroll
    for (int mf = 0; mf < 8; ++mf) {
      int rr = wm*128 + mf*16 + lm;
      afr[mf] = *(const bf16x8*)(Ab + rr*64 + soff);
    }
    STAGE_A(tn, qn);
    STAGE_B(tn, qn);

    __builtin_amdgcn_s_setprio(1);
    #pragma unroll
    for (int mf = 0; mf < 8; ++mf)
      #pragma unroll
      for (int nf = 0; nf < 4; ++nf)
        acc[mf][nf] = __builtin_amdgcn_mfma_f32_16x16x32_bf16(afr[mf], bfr[nf], acc[mf][nf], 0, 0, 0);
    __builtin_amdgcn_s_setprio(0);
  }

  #pragma unroll
  for (int mf = 0; mf < 8; ++mf) {
    #pragma unroll
    for (int r = 0; r < 4; ++r) {
      long m = bm0 + wm*128 + mf*16 + lq*4 + r;
      #pragma unroll
      for (int nf = 0; nf < 4; ++nf) {
        long n = bn0 + wn*64 + nf*16 + lm;
        float val = acc[mf][nf][r];
        if (RESID) val += resid[m * N + n];
        if (OUTF32) Cf[m * N + n] = val;
        else        Cb[m * N + n] = f2bf(val);
      }
    }
  }
}

// 64x64x64 NT matmul from LDS bf16 tiles (stride 72)
__device__ __forceinline__ void mm64(const u16* Ab, const u16* Bb,
                                     int lm, int lq, int wr, int wc, f32x4 acc[2][2])
{
  #pragma unroll
  for (int ks = 0; ks < 2; ++ks) {
    bf16x8 af[2], bfr[2];
    #pragma unroll
    for (int mi = 0; mi < 2; ++mi)
      af[mi] = *(const bf16x8*)(Ab + (wr*32 + mi*16 + lm)*72 + ks*32 + lq*8);
    #pragma unroll
    for (int ni = 0; ni < 2; ++ni)
      bfr[ni] = *(const bf16x8*)(Bb + (wc*32 + ni*16 + lm)*72 + ks*32 + lq*8);
    #pragma unroll
    for (int mi = 0; mi < 2; ++mi)
      #pragma unroll
      for (int ni = 0; ni < 2; ++ni)
        acc[mi][ni] = __builtin_amdgcn_mfma_f32_16x16x32_bf16(af[mi], bfr[ni], acc[mi][ni], 0, 0, 0);
  }
}

// ---------------- phase 1: per-chunk WY factors (sigmoid folded in) ----------------
__global__ __launch_bounds__(256) void chunk1(
    u16* __restrict__ kv, const float* __restrict__ bb, const float* __restrict__ bg,
    u16* __restrict__ p1buf, u16* __restrict__ r1buf)
{
  __shared__ __align__(16) u16 Kb[64*72];
  __shared__ __align__(16) u16 Utb[128*72];
  __shared__ __align__(16) u16 LpI[64*72];
  __shared__ __align__(16) u16 Abf[64*72];
  __shared__ __align__(16) u16 Adb[4*16*24];
  __shared__ float nrm2LS[64];
  __shared__ float aLS[64], ainvLS[64], bLS[64], bapLS[64];
  __shared__ float aCsh;

  const int tid = threadIdx.x;
  const int w = tid >> 6, l = tid & 63;
  const int lm = l & 15, lq = l >> 4;
  const int wr = w >> 1, wc = w & 1;
  const int bh = blockIdx.x & 63, ch = blockIdx.x >> 6;
  const int b = bh >> 4, h = bh & 15;

  const u16* kbase = kv + ((long)b*T_ + ch*64)*NPAD + h*64;
  const u16* vbase = kbase + 1024;

  #pragma unroll
  for (int it = 0; it < 2; ++it) {
    int c = tid + it*256;
    int r = c >> 3, seg = (c & 7)*8;
    *(u16x8*)(Kb  + r*72 + seg) = *(const u16x8*)(kbase + (long)r*NPAD + seg);
    *(u16x8*)(Utb + r*72 + seg) = *(const u16x8*)(vbase + (long)r*NPAD + seg);
  }
  #pragma unroll
  for (int z = 0; z < 8; ++z) {
    int idx = tid + z*256;
    int rr = idx >> 5, wd = idx & 31;
    ((unsigned int*)(Utb + (64 + rr)*72))[wd] = 0u;
  }
  if (tid < 64) {
    long rowg = ((long)b*T_ + ch*64 + tid) * NPAD;
    float blog = bf2f(kv[rowg + 2048 + h]) + bb[h];
    float glog = bf2f(kv[rowg + 2064 + h]) + bg[h];
    float bv = 1.f / (1.f + expf(-blog));
    float gv = 1.f / (1.f + expf(-glog));
    float av = gv;
    #pragma unroll
    for (int off = 1; off < 64; off <<= 1) {
      float o = __shfl_up(av, off, 64);
      if (tid >= off) av *= o;
    }
    float ap = __shfl_up(av, 1, 64);
    if (tid == 0) ap = 1.f;
    float aC = __shfl(av, 63, 64);
    aLS[tid] = av; ainvLS[tid] = 1.f/av; bLS[tid] = bv; bapLS[tid] = bv*ap;
    if (tid == 0) aCsh = aC;
  }
  __syncthreads();

  f32x4 gf[2][2];
  #pragma unroll
  for (int mi = 0; mi < 2; ++mi)
    #pragma unroll
    for (int ni = 0; ni < 2; ++ni) gf[mi][ni] = f32x4{0.f,0.f,0.f,0.f};
  mm64(Kb, Kb, lm, lq, wr, wc, gf);

  #pragma unroll
  for (int mi = 0; mi < 2; ++mi)
    #pragma unroll
    for (int ni = 0; ni < 2; ++ni)
      #pragma unroll
      for (int r = 0; r < 4; ++r) {
        int row = wr*32 + mi*16 + lq*4 + r, col = wc*32 + ni*16 + lm;
        if (row == col) nrm2LS[row] = gf[mi][ni][r];
      }
  __syncthreads();
  if (tid < 64) {
    float nv = 1.f / fmaxf(sqrtf(nrm2LS[tid]), 1e-12f);
    aLS[tid] *= nv; ainvLS[tid] *= nv; bapLS[tid] *= nv;
  }
  __syncthreads();

  float wv_[4][2][4];
  #pragma unroll
  for (int bi = 0; bi < 4; ++bi)
    #pragma unroll
    for (int ni = 0; ni < 2; ++ni) {
      int col = w*32 + ni*16 + lm;
      #pragma unroll
      for (int r = 0; r < 4; ++r) {
        int row = bi*16 + lq*4 + r;
        float sv = (col < 64) ? bf2f(Utb[row*72 + col]) : bf2f(Kb[row*72 + (col - 64)]);
        float coef = (col < 64) ? bLS[row] : bapLS[row];
        wv_[bi][ni][r] = coef * sv;
      }
    }

  #pragma unroll
  for (int mi = 0; mi < 2; ++mi)
    #pragma unroll
    for (int ni = 0; ni < 2; ++ni)
      #pragma unroll
      for (int r = 0; r < 4; ++r) {
        int row = wr*32 + mi*16 + lq*4 + r, col = wc*32 + ni*16 + lm;
        float gvl = gf[mi][ni][r];
        int rb = row >> 4, cb = col >> 4;
        Abf[row*72 + col] = f2bf((rb > cb) ? bapLS[row]*ainvLS[col]*gvl : 0.f);
        if (rb == cb)
          Adb[rb*384 + (row & 15)*24 + (col & 15)] =
              f2bf(((col & 15) < (row & 15)) ? bapLS[row]*ainvLS[col]*gvl : 0.f);
        LpI[row*72 + col] = f2bf((col < row) ? aLS[row]*ainvLS[col]*gvl
                                             : ((col == row) ? 1.f : 0.f));
      }
  __syncthreads();

  #pragma unroll
  for (int bi = 0; bi < 4; ++bi) {
    if (bi > 0) {
      f32x4 corr[2] = { f32x4{0.f,0.f,0.f,0.f}, f32x4{0.f,0.f,0.f,0.f} };
      const int nks = (bi*16 + 31) >> 5;
      #pragma unroll
      for (int ks = 0; ks < 2; ++ks) {
        if (ks < nks) {
          bf16x8 afr = *(const bf16x8*)(Abf + (bi*16 + lm)*72 + ks*32 + lq*8);
          #pragma unroll
          for (int ni = 0; ni < 2; ++ni) {
            bf16x8 bfrv = *(const bf16x8*)(Utb + (w*32 + ni*16 + lm)*72 + ks*32 + lq*8);
            corr[ni] = __builtin_amdgcn_mfma_f32_16x16x32_bf16(afr, bfrv, corr[ni], 0, 0, 0);
          }
        }
      }
      #pragma unroll
      for (int ni = 0; ni < 2; ++ni)
        #pragma unroll
        for (int r = 0; r < 4; ++r) wv_[bi][ni][r] -= corr[ni][r];
    }
    u16x8 ad0[4], ad1[4];
    #pragma unroll
    for (int r = 0; r < 4; ++r) {
      ad0[r] = *(const u16x8*)(Adb + bi*384 + (lq*4 + r)*24);
      ad1[r] = *(const u16x8*)(Adb + bi*384 + (lq*4 + r)*24 + 8);
    }
    #pragma unroll
    for (int i = 0; i < 16; ++i) {
      int src = ((i >> 2) << 4) | lm;
      float u0 = __shfl(wv_[bi][0][i & 3], src, 64);
      float u1 = __shfl(wv_[bi][1][i & 3], src, 64);
      #pragma unroll
      for (int r = 0; r < 4; ++r) {
        float ad = bf2f((i < 8) ? ad0[r][i] : ad1[r][i - 8]);
        wv_[bi][0][r] = fmaf(-ad, u0, wv_[bi][0][r]);
        wv_[bi][1][r] = fmaf(-ad, u1, wv_[bi][1][r]);
      }
    }
    #pragma unroll
    for (int ni = 0; ni < 2; ++ni) {
      int col = w*32 + ni*16 + lm;
      #pragma unroll
      for (int r = 0; r < 4; ++r)
        Utb[col*72 + bi*16 + lq*4 + r] = f2bf(wv_[bi][ni][r]);
    }
  }
  __syncthreads();

  const long pr_base = (((long)bh*64 + ch)*64);
  u16* qdst = kv + ((long)b*T_ + ch*64)*NPAD + h*64;
  u16* mdst = qdst + 1024;
  f32x4 acc[2][2];

  // P1[i][v]
  #pragma unroll
  for (int mi = 0; mi < 2; ++mi)
    #pragma unroll
    for (int ni = 0; ni < 2; ++ni) acc[mi][ni] = f32x4{0.f,0.f,0.f,0.f};
  mm64(LpI, Utb, lm, lq, wr, wc, acc);
  #pragma unroll
  for (int mi = 0; mi < 2; ++mi)
    #pragma unroll
    for (int ni = 0; ni < 2; ++ni)
      #pragma unroll
      for (int r = 0; r < 4; ++r) {
        int row = wr*32 + mi*16 + lq*4 + r, col = wc*32 + ni*16 + lm;
        p1buf[(pr_base + row)*64 + col] = f2bf(acc[mi][ni][r]);
      }

  // Q
  #pragma unroll
  for (int mi = 0; mi < 2; ++mi)
    #pragma unroll
    for (int ni = 0; ni < 2; ++ni) acc[mi][ni] = f32x4{0.f,0.f,0.f,0.f};
  mm64(LpI, Utb + 64*72, lm, lq, wr, wc, acc);
  #pragma unroll
  for (int mi = 0; mi < 2; ++mi)
    #pragma unroll
    for (int ni = 0; ni < 2; ++ni)
      #pragma unroll
      for (int r = 0; r < 4; ++r) {
        int row = wr*32 + mi*16 + lq*4 + r, col = wc*32 + ni*16 + lm;
        float val = aLS[row]*bf2f(Kb[row*72 + col]) - acc[mi][ni][r];
        qdst[(long)row*NPAD + col] = f2bf(val);
      }

  // Ktb into Abf
  {
    int s = tid & 63, kk0 = (tid >> 6) * 16;
    float coef = aCsh * ainvLS[s];
    #pragma unroll
    for (int j = 0; j < 16; ++j)
      Abf[(kk0 + j)*72 + s] = f2bf(coef * bf2f(Kb[s*72 + kk0 + j]));
  }
  __syncthreads();

  // R1[k][v]
  #pragma unroll
  for (int mi = 0; mi < 2; ++mi)
    #pragma unroll
    for (int ni = 0; ni < 2; ++ni) acc[mi][ni] = f32x4{0.f,0.f,0.f,0.f};
  mm64(Abf, Utb, lm, lq, wr, wc, acc);
  #pragma unroll
  for (int mi = 0; mi < 2; ++mi)
    #pragma unroll
    for (int ni = 0; ni < 2; ++ni)
      #pragma unroll
      for (int r = 0; r < 4; ++r) {
        int row = wr*32 + mi*16 + lq*4 + r, col = wc*32 + ni*16 + lm;
        r1buf[(pr_base + row)*64 + col] = f2bf(acc[mi][ni][r]);
      }

  // M
  #pragma unroll
  for (int mi = 0; mi < 2; ++mi)
    #pragma unroll
    for (int ni = 0; ni < 2; ++ni) acc[mi][ni] = f32x4{0.f,0.f,0.f,0.f};
  mm64(Abf, Utb + 64*72, lm, lq, wr, wc, acc);
  #pragma unroll
  for (int mi = 0; mi < 2; ++mi)
    #pragma unroll
    for (int ni = 0; ni < 2; ++ni)
      #pragma unroll
      for (int r = 0; r < 4; ++r) {
        int row = wr*32 + mi*16 + lq*4 + r, col = wc*32 + ni*16 + lm;
        float val = ((row == col) ? aCsh : 0.f) - acc[mi][ni][r];
        mdst[(long)row*NPAD + col] = f2bf(val);
      }
}

// ---------------- phase 2: sequential chunk recurrence (single-barrier dbuf) ----------------
struct PF { u16x8 qf0, qf1, mf0, mf1; u16x4 p1, r1; };

__global__ __launch_bounds__(256) void chunk2(
    const u16* __restrict__ kv, const u16* __restrict__ p1buf, const u16* __restrict__ r1buf,
    u16* __restrict__ outb)
{
  __shared__ __align__(16) u16 Zb[2][16*72];
  __shared__ __align__(16) u16 ot[2][64*24];
  const int tid = threadIdx.x;
  const int wcv = tid >> 6, l = tid & 63;
  const int lm = l & 15, lq = l >> 4;
  const int bh = blockIdx.x & 63, vg = blockIdx.x >> 6;
  const int b = bh >> 4, h = bh & 15;

  for (int idx = tid; idx < 16*72/2; idx += 256) ((unsigned int*)Zb[0])[idx] = 0u;

  const u16* pbase = p1buf + (long)bh*64*4096;
  const u16* rbase = r1buf + (long)bh*64*4096;
  const int i2 = tid >> 2, q4 = tid & 3;

  auto LOADPF = [&](int ch, PF& p){
    long rq = ((long)b*T_ + ch*64 + wcv*16 + lm)*NPAD + h*64 + lq*8;
    p.qf0 = *(const u16x8*)(kv + rq);
    p.qf1 = *(const u16x8*)(kv + rq + 32);
    p.mf0 = *(const u16x8*)(kv + rq + 1024);
    p.mf1 = *(const u16x8*)(kv + rq + 1024 + 32);
    long pv = (long)ch*4096 + (wcv*16 + lm)*64 + vg*16 + lq*4;
    p.p1 = *(const u16x4*)(pbase + pv);
    p.r1 = *(const u16x4*)(rbase + pv);
  };

  PF A, Bp;
  LOADPF(0, A);
  __syncthreads();

  auto STEP = [&](int ch, PF& use, PF& pre){
    int p = ch & 1;
    bf16x8 za0 = *(const bf16x8*)(Zb[p] + lm*72 + lq*8);
    bf16x8 za1 = *(const bf16x8*)(Zb[p] + lm*72 + 32 + lq*8);
    if (ch < 63) LOADPF(ch + 1, pre);
    f32x4 accO = { bf2f(use.p1[0]), bf2f(use.p1[1]), bf2f(use.p1[2]), bf2f(use.p1[3]) };
    accO = __builtin_amdgcn_mfma_f32_16x16x32_bf16(za0, as_bf(use.qf0), accO, 0, 0, 0);
    accO = __builtin_amdgcn_mfma_f32_16x16x32_bf16(za1, as_bf(use.qf1), accO, 0, 0, 0);
    f32x4 accS = { bf2f(use.r1[0]), bf2f(use.r1[1]), bf2f(use.r1[2]), bf2f(use.r1[3]) };
    accS = __builtin_amdgcn_mfma_f32_16x16x32_bf16(za0, as_bf(use.mf0), accS, 0, 0, 0);
    accS = __builtin_amdgcn_mfma_f32_16x16x32_bf16(za1, as_bf(use.mf1), accS, 0, 0, 0);
    if (ch > 0) {
      u16x4 ov = *(const u16x4*)(ot[p^1] + i2*24 + q4*4);
      *(u16x4*)(outb + ((long)b*T_ + (ch-1)*64 + i2)*D_ + h*64 + vg*16 + q4*4) = ov;
    }
    #pragma unroll
    for (int r = 0; r < 4; ++r) ot[p][(wcv*16 + lm)*24 + lq*4 + r] = f2bf(accO[r]);
    #pragma unroll
    for (int r = 0; r < 4; ++r) Zb[p^1][(lq*4 + r)*72 + wcv*16 + lm] = f2bf(accS[r]);
    __syncthreads();
  };

  for (int c2 = 0; c2 < 32; ++c2) {
    STEP(2*c2,     A, Bp);
    STEP(2*c2 + 1, Bp, A);
  }
  {
    u16x4 ov = *(const u16x4*)(ot[1] + i2*24 + q4*4);
    *(u16x4*)(outb + ((long)b*T_ + 63*64 + i2)*D_ + h*64 + vg*16 + q4*4) = ov;
  }
}

extern "C" void kernel_launch(void* const* d_in, const int* in_sizes, int n_in,
                              void* d_out, int out_size, void* d_ws, size_t ws_size,
                              hipStream_t stream) {
  const float* x     = (const float*)d_in[0];
  const float* normw = (const float*)d_in[1];
  const float* Wk    = (const float*)d_in[2];
  const float* Wv    = (const float*)d_in[3];
  const float* Wo    = (const float*)d_in[4];
  const float* Wb    = (const float*)d_in[5];
  const float* bb    = (const float*)d_in[6];
  const float* Wg    = (const float*)d_in[7];
  const float* bg    = (const float*)d_in[8];
  float* y = (float*)d_out;

  char* ws = (char*)d_ws;
  u16* xn    = (u16*)ws;   ws += (long)ROWS * D_ * 2;      // 33.5 MB (reused as P1)
  u16* Wcomb = (u16*)ws;   ws += (long)NPAD * D_ * 2;      // 4.7 MB
  u16* Wob   = (u16*)ws;   ws += (long)D_ * D_ * 2;        // 2 MB
  u16* kvb   = (u16*)ws;   ws += (long)ROWS * NPAD * 2;    // 75.5 MB (k,v -> Q,M in place)
  u16* outb  = (u16*)ws;   ws += (long)ROWS * D_ * 2;      // 33.5 MB
  u16* r1b   = (u16*)ws;   ws += (long)64 * 64 * 4096 * 2; // 33.5 MB  R1

  const int LDSB = 3 * 32768;   // 96 KB, 3-buffer distance-2 pipeline (R6-proven)
  if (hipFuncSetAttribute(reinterpret_cast<const void*>(gemm256<0,0>),
        hipFuncAttributeMaxDynamicSharedMemorySize, LDSB) != hipSuccess) return;
  if (hipFuncSetAttribute(reinterpret_cast<const void*>(gemm256<1,1>),
        hipFuncAttributeMaxDynamicSharedMemorySize, LDSB) != hipSuccess) return;

  const long prep_total = (long)NPAD * D_ + (long)D_ * D_;   // 3,407,872
  const unsigned prep_blocks = (unsigned)(prep_total / 256); // 13312
  prep_rms<<<dim3(ROWS + prep_blocks), dim3(256), 0, stream>>>(
      x, normw, Wk, Wv, Wb, Wg, Wo, xn, Wcomb, Wob);
  gemm256<0, 0><<<dim3(NPAD / 256, ROWS / 256), dim3(512), LDSB, stream>>>(
      xn, Wcomb, kvb, (float*)nullptr, (const float*)nullptr, ROWS, NPAD, D_);
  chunk1<<<dim3(4096), dim3(256), 0, stream>>>(kvb, bb, bg, xn, r1b);
  chunk2<<<dim3(256), dim3(256), 0, stream>>>(kvb, xn, r1b, outb);
  gemm256<1, 1><<<dim3(D_ / 256, ROWS / 256), dim3(512), LDSB, stream>>>(
      outb, Wob, (u16*)nullptr, y, x, ROWS, D_, D_);
}